// Round 20
// baseline (6582.882 us; speedup 1.0000x reference)
//
#include <hip/hip_runtime.h>
#include <stdint.h>

typedef unsigned short u16;
typedef __attribute__((ext_vector_type(4))) float f32x4;
typedef __attribute__((ext_vector_type(8))) __bf16 bf16x8;
typedef __attribute__((ext_vector_type(8))) unsigned short u16x8;

__device__ __forceinline__ u16 f2bf(float f) {
  unsigned u = __builtin_bit_cast(unsigned, f);
  u = (u + 0x7fffu + ((u >> 16) & 1u)) >> 16;
  return (u16)u;
}

typedef __attribute__((address_space(1))) const void gvoid_t;
typedef __attribute__((address_space(3))) void lvoid_t;

__device__ __forceinline__ void gload_lds16(const void* g, void* l) {
  __builtin_amdgcn_global_load_lds((gvoid_t*)g, (lvoid_t*)l, 16, 0, 0);
}

// ---------------- fused prologue: dequant W_up + cvt x->bf16, one launch (role-split)
__global__ __launch_bounds__(256)
void prologue_kernel(const int* __restrict__ q, const float* __restrict__ s,
                     const int* __restrict__ z, u16* __restrict__ w, int K, int dqB,
                     const float* __restrict__ x, u16* __restrict__ xb) {
  const int bid = blockIdx.x;
  if (bid < dqB) {
    const int cpr = K >> 11;              // chunks per row (2048 elems each)
    const int row = bid / cpr;
    const int k = (bid % cpr) * 2048 + (int)threadIdx.x * 8;
    const int ng = K >> 7;
    const int g = k >> 7;
    const float sv = s[(size_t)row * ng + g];
    const float zv = (float)z[(size_t)row * ng + g];
    const int4* qp = (const int4*)(q + (size_t)row * K + k);
    const int4 a = qp[0], b = qp[1];
    u16x8 o;
    o[0] = f2bf(((float)a.x - zv) * sv);
    o[1] = f2bf(((float)a.y - zv) * sv);
    o[2] = f2bf(((float)a.z - zv) * sv);
    o[3] = f2bf(((float)a.w - zv) * sv);
    o[4] = f2bf(((float)b.x - zv) * sv);
    o[5] = f2bf(((float)b.y - zv) * sv);
    o[6] = f2bf(((float)b.z - zv) * sv);
    o[7] = f2bf(((float)b.w - zv) * sv);
    *reinterpret_cast<u16x8*>(w + (size_t)row * K + k) = o;
  } else {
    const size_t i = ((size_t)(bid - dqB) * 256 + threadIdx.x) << 3;
    const float4* p = (const float4*)(x + i);
    const float4 a = p[0], b = p[1];
    u16x8 o;
    o[0] = f2bf(a.x); o[1] = f2bf(a.y); o[2] = f2bf(a.z); o[3] = f2bf(a.w);
    o[4] = f2bf(b.x); o[5] = f2bf(b.y); o[6] = f2bf(b.z); o[7] = f2bf(b.w);
    *reinterpret_cast<u16x8*>(xb + i) = o;
  }
}

// ---------------- standalone dequant (serial fallback path only)
__global__ __launch_bounds__(256)
void dequant_kernel(const int* __restrict__ q, const float* __restrict__ s,
                    const int* __restrict__ z, u16* __restrict__ w, int K) {
  const int row = blockIdx.y;
  const int k = (blockIdx.x * 256 + threadIdx.x) << 3;
  const int ng = K >> 7;
  const int g = k >> 7;
  const float sv = s[(size_t)row * ng + g];
  const float zv = (float)z[(size_t)row * ng + g];
  const int4* qp = (const int4*)(q + (size_t)row * K + k);
  const int4 a = qp[0], b = qp[1];
  u16x8 o;
  o[0] = f2bf(((float)a.x - zv) * sv);
  o[1] = f2bf(((float)a.y - zv) * sv);
  o[2] = f2bf(((float)a.z - zv) * sv);
  o[3] = f2bf(((float)a.w - zv) * sv);
  o[4] = f2bf(((float)b.x - zv) * sv);
  o[5] = f2bf(((float)b.y - zv) * sv);
  o[6] = f2bf(((float)b.z - zv) * sv);
  o[7] = f2bf(((float)b.w - zv) * sv);
  *reinterpret_cast<u16x8*>(w + (size_t)row * K + k) = o;
}

// ================= 256x256 BK=32 GEMM, 2 blocks/CU (GEMM1 only) ================
// LDS 64 KiB (2 bufs x 256x32 x2 arrays) -> 2 co-resident blocks/CU; 16 waves/CU
// at <=128 VGPR (launch_bounds(512,4)). Mechanism: block A's barrier/drain stalls
// are covered by block B's MFMA (m114 cross-wave overlap) — replaces counted-lgkm
// finesse with occupancy. Per K-tile (one 16x16x32 kstep):
//   ph1: BARO; rd all 12 frags {b1,a1,a2}; lgkm(0); MFMA(a1*b1 -> acc[0-3])
//   ph2: BARO; stg A(T+2),B(T+2)->p (4 loads); MFMA(a2*b1 -> acc[4-7]); GATE vmcnt(4)
// Stage-safety: BARO(ph2) follows every wave's ph1 lgkm(0) which drains ALL its
// buf-p reads -> overwrite of p is race-free. Gate invariant: entering T,
// outstanding = {A,B}(T+1) (4); +{A,B}(T+2) at ph2 -> 8; vmcnt(4) completes
// exactly T+1's inputs, leaves T+2 in flight; gate precedes next tile's BARO (R10).
// Swizzle (4 chunks/row): chunk ^= (row>>1)&3; read koff = ((lane>>4)^((lr>>1)&3))<<4.
// Bank enumeration: 8 lanes per 4-bank window, perfectly uniform (b128 minimum).
template<bool RELU2>
__global__ __launch_bounds__(512, 4)
void gemm256_bk32(const u16* __restrict__ Ap, const u16* __restrict__ Bp,
                  void* __restrict__ Cptr, int M, int N, int K, int gemmNwg,
                  const int* __restrict__ q2, const float* __restrict__ s2,
                  const int* __restrict__ z2, u16* __restrict__ w2) {
  __shared__ __align__(16) u16 As[2][256][32];
  __shared__ __align__(16) u16 Bs[2][256][32];

  if ((int)blockIdx.x >= gemmNwg) {
    // ---- dequant role: rows 2b, 2b+1 of q2 [.. x 14336] -> w2 ----
    const int b = (int)blockIdx.x - gemmNwg;
    const int I2 = 14336, ng = I2 >> 7;
#pragma unroll
    for (int itc = 0; itc < 7; ++itc) {
      const int inner = itc * 4096 + (int)threadIdx.x * 8;
      const int r = (inner >= I2) ? 1 : 0;
      const int k = inner - r * I2;
      const int row = 2 * b + r;
      const int g = k >> 7;
      const float sv = s2[(size_t)row * ng + g];
      const float zv = (float)z2[(size_t)row * ng + g];
      const int4* qp = (const int4*)(q2 + (size_t)row * I2 + k);
      const int4 qa = qp[0], qb = qp[1];
      u16x8 o;
      o[0] = f2bf(((float)qa.x - zv) * sv);
      o[1] = f2bf(((float)qa.y - zv) * sv);
      o[2] = f2bf(((float)qa.z - zv) * sv);
      o[3] = f2bf(((float)qa.w - zv) * sv);
      o[4] = f2bf(((float)qb.x - zv) * sv);
      o[5] = f2bf(((float)qb.y - zv) * sv);
      o[6] = f2bf(((float)qb.z - zv) * sv);
      o[7] = f2bf(((float)qb.w - zv) * sv);
      *reinterpret_cast<u16x8*>(w2 + (size_t)row * I2 + k) = o;
    }
    return;
  }

  const int tid = threadIdx.x;
  const int lane = tid & 63;
  const int wid = tid >> 6;
  const int wr = wid >> 2, wc = wid & 3;

  const int nbx = N >> 8;
  const int nwg = gemmNwg;
  int bid = blockIdx.x;
  bid = (bid & 7) * (nwg >> 3) + (bid >> 3);   // XCD swizzle (gemmNwg % 8 == 0)
  const int m0 = (bid / nbx) << 8;             // n-fastest
  const int n0 = (bid % nbx) << 8;

  const int srow = tid >> 2;        // staging row within 128-row sweep
  const int scol = tid & 3;         // staging 16B chunk (4 per row)
  const int lr = lane & 15;
  const int koff = ((lane >> 4) ^ ((lr >> 1) & 3)) << 4;  // swizzled chunk byte offset

  const char* baA0 = (const char*)&As[0][0][0] + (wr * 128 + lr) * 64;
  const char* baA1 = baA0 + 16384;
  const char* baB0 = (const char*)&Bs[0][0][0] + (wc * 64 + lr) * 64;
  const char* baB1 = baB0 + 16384;

  f32x4 acc[8][4] = {};
  bf16x8 a1[4], a2[4], b1[4];

  const int nk = K >> 5;

#define STG_A32(bufi, kt) do { _Pragma("unroll") \
  for (int l_ = 0; l_ < 2; ++l_) { \
    const int r_ = l_ * 128 + srow; \
    gload_lds16(Ap + (size_t)(m0 + r_) * K + (size_t)((kt) << 5) + ((scol ^ ((r_ >> 1) & 3)) << 3), \
                &As[bufi][r_][scol << 3]); } } while (0)
#define STG_B32(bufi, kt) do { _Pragma("unroll") \
  for (int l_ = 0; l_ < 2; ++l_) { \
    const int r_ = l_ * 128 + srow; \
    gload_lds16(Bp + (size_t)(n0 + r_) * K + (size_t)((kt) << 5) + ((scol ^ ((r_ >> 1) & 3)) << 3), \
                &Bs[bufi][r_][scol << 3]); } } while (0)
#define RD_A32(base, half, dst) do { _Pragma("unroll") \
  for (int i_ = 0; i_ < 4; ++i_) \
    dst[i_] = *reinterpret_cast<const bf16x8*>((base) + ((half) * 4 + i_) * 1024 + koff); } while (0)
#define RD_B32(base, dst) do { _Pragma("unroll") \
  for (int j_ = 0; j_ < 4; ++j_) \
    dst[j_] = *reinterpret_cast<const bf16x8*>((base) + j_ * 1024 + koff); } while (0)
#define MFMA16(ASET, BSET, I0) do { _Pragma("unroll") \
  for (int i_ = 0; i_ < 4; ++i_) { _Pragma("unroll") \
    for (int j_ = 0; j_ < 4; ++j_) \
      acc[(I0) + i_][j_] = __builtin_amdgcn_mfma_f32_16x16x32_bf16( \
        ASET[i_], BSET[j_], acc[(I0) + i_][j_], 0, 0, 0); } } while (0)
#define BARO() do { asm volatile("" ::: "memory"); __builtin_amdgcn_s_barrier(); \
  asm volatile("" ::: "memory"); } while (0)
#define LGKM0() do { asm volatile("s_waitcnt lgkmcnt(0)" ::: "memory"); \
  __builtin_amdgcn_sched_barrier(0); } while (0)
#define GATE4 asm volatile("s_waitcnt vmcnt(4)" ::: "memory")
#define PRIO(Q) do { __builtin_amdgcn_s_setprio(1); Q; __builtin_amdgcn_s_setprio(0); } while (0)
// One BK=32 tile in buf p: SA/SB = stage {A,B}(T+2) -> p.
#define TILE32(bA, bB, SA, SB) do { \
  BARO(); \
  RD_B32(bB, b1); RD_A32(bA, 0, a1); RD_A32(bA, 1, a2); \
  LGKM0(); \
  PRIO(MFMA16(a1, b1, 0)); \
  BARO(); \
  SA; SB; \
  PRIO(MFMA16(a2, b1, 4)); \
  GATE4; \
} while (0)

  // prologue: {A,B}(0)->buf0, {A,B}(1)->buf1 (8 loads); vmcnt(4) completes tile0
  STG_A32(0, 0); STG_B32(0, 0);
  STG_A32(1, 1); STG_B32(1, 1);
  asm volatile("s_waitcnt vmcnt(4)" ::: "memory");

  const int nit = nk >> 1;
  for (int it = 0; it < nit; ++it) {
    int t2 = 2 * it + 2; if (t2 >= nk) t2 -= nk;   // wrap: tail stages are dummies
    int t3 = 2 * it + 3; if (t3 >= nk) t3 -= nk;
    TILE32(baA0, baB0, STG_A32(0, t2), STG_B32(0, t2));
    TILE32(baA1, baB1, STG_A32(1, t3), STG_B32(1, t3));
  }
  asm volatile("s_waitcnt vmcnt(0) lgkmcnt(0)" ::: "memory");

  // epilogue: C/D layout col = lane&15, row = (lane>>4)*4 + reg  [m89-verified]
  const int crow = (lane >> 4) << 2;
  const int ccol = lane & 15;
#pragma unroll
  for (int i = 0; i < 8; ++i) {
#pragma unroll
    for (int j = 0; j < 4; ++j) {
#pragma unroll
      for (int q = 0; q < 4; ++q) {
        const int m = m0 + wr * 128 + i * 16 + crow + q;
        const int n = n0 + wc * 64 + j * 16 + ccol;
        const float v = acc[i][j][q];
        if constexpr (RELU2) {
          const float r = fmaxf(v, 0.f);
          ((u16*)Cptr)[(size_t)m * N + n] = f2bf(r * r);
        } else {
          ((float*)Cptr)[(size_t)m * N + n] = v;
        }
      }
    }
  }
#undef STG_A32
#undef STG_B32
#undef RD_A32
#undef RD_B32
#undef MFMA16
#undef BARO
#undef LGKM0
#undef GATE4
#undef PRIO
#undef TILE32
}

// ================= 256x256 BK=64 GEMM (R11/R19 schedule) — GEMM2 + fallback ====
template<bool RELU2>
__global__ __launch_bounds__(512, 2)
void gemm256(const u16* __restrict__ Ap, const u16* __restrict__ Bp,
             void* __restrict__ Cptr, int M, int N, int K, int gemmNwg,
             const int* __restrict__ q2, const float* __restrict__ s2,
             const int* __restrict__ z2, u16* __restrict__ w2) {
  __shared__ __align__(16) u16 As[2][256][64];
  __shared__ __align__(16) u16 Bs[2][256][64];

  if ((int)blockIdx.x >= gemmNwg) {
    const int b = (int)blockIdx.x - gemmNwg;
    const int I2 = 14336, ng = I2 >> 7;
#pragma unroll
    for (int itc = 0; itc < 7; ++itc) {
      const int inner = itc * 4096 + (int)threadIdx.x * 8;
      const int r = (inner >= I2) ? 1 : 0;
      const int k = inner - r * I2;
      const int row = 2 * b + r;
      const int g = k >> 7;
      const float sv = s2[(size_t)row * ng + g];
      const float zv = (float)z2[(size_t)row * ng + g];
      const int4* qp = (const int4*)(q2 + (size_t)row * I2 + k);
      const int4 qa = qp[0], qb = qp[1];
      u16x8 o;
      o[0] = f2bf(((float)qa.x - zv) * sv);
      o[1] = f2bf(((float)qa.y - zv) * sv);
      o[2] = f2bf(((float)qa.z - zv) * sv);
      o[3] = f2bf(((float)qa.w - zv) * sv);
      o[4] = f2bf(((float)qb.x - zv) * sv);
      o[5] = f2bf(((float)qb.y - zv) * sv);
      o[6] = f2bf(((float)qb.z - zv) * sv);
      o[7] = f2bf(((float)qb.w - zv) * sv);
      *reinterpret_cast<u16x8*>(w2 + (size_t)row * I2 + k) = o;
    }
    return;
  }

  const int tid = threadIdx.x;
  const int lane = tid & 63;
  const int wid = tid >> 6;
  const int wr = wid >> 2, wc = wid & 3;

  const int nbx = N >> 8;
  const int nwg = gemmNwg;
  int bid = blockIdx.x;
  bid = (bid & 7) * (nwg >> 3) + (bid >> 3);
  const int m0 = (bid / nbx) << 8;
  const int n0 = (bid % nbx) << 8;

  const int srow = tid >> 3;
  const int scol = tid & 7;
  const int lr = lane & 15;
  const int lk = (lane >> 4) << 3;
  const int xorc = (lr & 7) << 3;

  const char* baA0 = (const char*)&As[0][0][0] + (wr * 128 + lr) * 128;
  const char* baA1 = baA0 + 32768;
  const char* baB0 = (const char*)&Bs[0][0][0] + (wc * 64 + lr) * 128;
  const char* baB1 = baB0 + 32768;
  const int koff0 = (lk ^ xorc) * 2;

  f32x4 acc[8][4] = {};
  bf16x8 a1[4], a2[4], a3[4], a4[4], b1[4], b2[4];

  const int nk = K >> 6;

#define STG_A(bufi, h, kt) do { _Pragma("unroll") \
  for (int l_ = 0; l_ < 2; ++l_) { \
    const int r_ = (h) * 128 + l_ * 64 + srow; \
    gload_lds16(Ap + (size_t)(m0 + r_) * K + (size_t)((kt) << 6) + ((scol ^ (srow & 7)) << 3), \
                &As[bufi][r_][scol << 3]); } } while (0)
#define STG_B(bufi, h, kt) do { _Pragma("unroll") \
  for (int l_ = 0; l_ < 2; ++l_) { \
    const int r_ = (h) * 128 + l_ * 64 + srow; \
    gload_lds16(Bp + (size_t)(n0 + r_) * K + (size_t)((kt) << 6) + ((scol ^ (srow & 7)) << 3), \
                &Bs[bufi][r_][scol << 3]); } } while (0)
#define RD_A(base, ks, half, dst) do { _Pragma("unroll") \
  for (int i_ = 0; i_ < 4; ++i_) \
    dst[i_] = *reinterpret_cast<const bf16x8*>( \
      (base) + ((half) * 4 + i_) * 2048 + (koff0 ^ ((ks) * 64))); } while (0)
#define RD_B(base, ks, dst) do { _Pragma("unroll") \
  for (int j_ = 0; j_ < 4; ++j_) \
    dst[j_] = *reinterpret_cast<const bf16x8*>( \
      (base) + j_ * 2048 + (koff0 ^ ((ks) * 64))); } while (0)
#define MFMA16(ASET, BSET, I0) do { _Pragma("unroll") \
  for (int i_ = 0; i_ < 4; ++i_) { _Pragma("unroll") \
    for (int j_ = 0; j_ < 4; ++j_) \
      acc[(I0) + i_][j_] = __builtin_amdgcn_mfma_f32_16x16x32_bf16( \
        ASET[i_], BSET[j_], acc[(I0) + i_][j_], 0, 0, 0); } } while (0)
#define BARO() do { asm volatile("" ::: "memory"); __builtin_amdgcn_s_barrier(); \
  asm volatile("" ::: "memory"); } while (0)
#define LGKM(n) do { asm volatile("s_waitcnt lgkmcnt(" #n ")" ::: "memory"); \
  __builtin_amdgcn_sched_barrier(0); } while (0)
#define SB0 __builtin_amdgcn_sched_barrier(0)
#define GATE4 asm volatile("s_waitcnt vmcnt(4)" ::: "memory")
#define PRIO(Q) do { __builtin_amdgcn_s_setprio(1); Q; __builtin_amdgcn_s_setprio(0); } while (0)
#define TILE4(bA, bB, SA1, SA2, SB3, SB4) do { \
  BARO(); \
  RD_B(bB, 0, b1); RD_A(bA, 0, 0, a1); \
  LGKM(0); \
  SA1; \
  PRIO(MFMA16(a1, b1, 0)); \
  SB0; RD_B(bB, 1, b2); SB0; RD_A(bA, 0, 1, a2); SB0; RD_A(bA, 1, 1, a4); SB0; RD_A(bA, 1, 0, a3); \
  BARO(); \
  LGKM(8); \
  SA2; \
  PRIO(MFMA16(a2, b1, 4)); \
  BARO(); \
  LGKM(4); \
  SB3; \
  PRIO(MFMA16(a4, b2, 4)); \
  BARO(); \
  LGKM(0); \
  SB4; \
  PRIO(MFMA16(a3, b2, 0)); \
  GATE4; \
} while (0)

  STG_A(0, 0, 0); STG_A(0, 1, 0);
  STG_B(0, 0, 0); STG_B(0, 1, 0);
  STG_B(1, 0, 1); STG_B(1, 1, 1);
  asm volatile("s_waitcnt vmcnt(4)" ::: "memory");

  const int nit = nk >> 1;
  for (int it = 0; it < nit; ++it) {
    const int t1 = 2 * it + 1;
    int t2 = 2 * it + 2; if (t2 >= nk) t2 -= nk;
    int t3 = 2 * it + 3; if (t3 >= nk) t3 -= nk;
    TILE4(baA0, baB0, STG_A(1, 0, t1), STG_A(1, 1, t1), STG_B(0, 0, t2), STG_B(0, 1, t2));
    TILE4(baA1, baB1, STG_A(0, 0, t2), STG_A(0, 1, t2), STG_B(1, 0, t3), STG_B(1, 1, t3));
  }
  asm volatile("s_waitcnt vmcnt(0) lgkmcnt(0)" ::: "memory");

  const int crow = (lane >> 4) << 2;
  const int ccol = lane & 15;
#pragma unroll
  for (int i = 0; i < 8; ++i) {
#pragma unroll
    for (int j = 0; j < 4; ++j) {
#pragma unroll
      for (int q = 0; q < 4; ++q) {
        const int m = m0 + wr * 128 + i * 16 + crow + q;
        const int n = n0 + wc * 64 + j * 16 + ccol;
        const float v = acc[i][j][q];
        if constexpr (RELU2) {
          const float r = fmaxf(v, 0.f);
          ((u16*)Cptr)[(size_t)m * N + n] = f2bf(r * r);
        } else {
          ((float*)Cptr)[(size_t)m * N + n] = v;
        }
      }
    }
  }
#undef STG_A
#undef STG_B
#undef RD_A
#undef RD_B
#undef MFMA16
#undef BARO
#undef LGKM
#undef SB0
#undef GATE4
#undef PRIO
#undef TILE4
}

extern "C" void kernel_launch(void* const* d_in, const int* in_sizes, int n_in,
                              void* d_out, int out_size, void* d_ws, size_t ws_size,
                              hipStream_t stream) {
  const float* x    = (const float*)d_in[0];
  const int*   q_up = (const int*)d_in[1];
  const float* s_up = (const float*)d_in[2];
  const int*   z_up = (const int*)d_in[3];
  const int*   q_dn = (const int*)d_in[4];
  const float* s_dn = (const float*)d_in[5];
  const int*   z_dn = (const int*)d_in[6];
  float* y = (float*)d_out;

  const int H = 4096, I = 14336;
  const int M = in_sizes[0] / H;  // 4096 tokens

  const size_t wbytes = (size_t)I * H * 2;
  const size_t abytes = (size_t)M * I * 2;
  const size_t xbytes = (size_t)M * H * 2;
  u16* wbuf  = (u16*)d_ws;
  u16* abuf  = (u16*)((char*)d_ws + wbytes);
  u16* xbf   = (u16*)((char*)d_ws + wbytes + abytes);
  u16* wbuf2 = (u16*)((char*)d_ws + wbytes + abytes + xbytes);
  if (ws_size < wbytes + abytes + xbytes) return;
  const bool fused = ws_size >= 2 * wbytes + abytes + xbytes;

  const int dqB = I * (H >> 11);                      // 28672
  const int cvB = (int)(((size_t)M * H) >> 11);       // 8192
  prologue_kernel<<<dim3(dqB + cvB), 256, 0, stream>>>(q_up, s_up, z_up, wbuf, H, dqB, x, xbf);

  const int g1 = (M / 256) * (I / 256);   // 896, %8==0
  const int g2 = (M / 256) * (H / 256);   // 256, %8==0
  if (fused) {
    // GEMM1 (BK=32, 2 blocks/CU) + fused dequant2 tail role
    gemm256_bk32<true><<<dim3(g1 + H / 2), 512, 0, stream>>>(
        xbf, wbuf, abuf, M, I, H, g1, q_dn, s_dn, z_dn, wbuf2);
    // GEMM2 (proven BK=64 R11 schedule)
    gemm256<false><<<dim3(g2), 512, 0, stream>>>(
        abuf, wbuf2, y, M, H, I, g2, nullptr, nullptr, nullptr, nullptr);
  } else {
    gemm256<true><<<dim3(g1), 512, 0, stream>>>(
        xbf, wbuf, abuf, M, I, H, g1, nullptr, nullptr, nullptr, nullptr);
    dequant_kernel<<<dim3(I / 8 / 256, H), 256, 0, stream>>>(q_dn, s_dn, z_dn, wbuf, I);
    gemm256<false><<<dim3(g2), 512, 0, stream>>>(
        abuf, wbuf, y, M, H, I, g2, nullptr, nullptr, nullptr, nullptr);
  }
}

// Round 21
// 916.751 us; speedup vs baseline: 7.1807x; 7.1807x over previous
//
#include <hip/hip_runtime.h>
#include <stdint.h>

typedef unsigned short u16;
typedef __attribute__((ext_vector_type(4))) float f32x4;
typedef __attribute__((ext_vector_type(8))) __bf16 bf16x8;
typedef __attribute__((ext_vector_type(8))) unsigned short u16x8;

__device__ __forceinline__ u16 f2bf(float f) {
  unsigned u = __builtin_bit_cast(unsigned, f);
  u = (u + 0x7fffu + ((u >> 16) & 1u)) >> 16;
  return (u16)u;
}

typedef __attribute__((address_space(1))) const void gvoid_t;
typedef __attribute__((address_space(3))) void lvoid_t;

__device__ __forceinline__ void gload_lds16(const void* g, void* l) {
  __builtin_amdgcn_global_load_lds((gvoid_t*)g, (lvoid_t*)l, 16, 0, 0);
}

// ---------------- fused prologue: dequant W_up + cvt x->bf16, one launch (role-split)
// blocks [0, dqB): dequant row = b / (K/2048), 2048-elem chunk = b % (K/2048)
// blocks [dqB, dqB+cvB): cvt chunk of 2048 floats
__global__ __launch_bounds__(256)
void prologue_kernel(const int* __restrict__ q, const float* __restrict__ s,
                     const int* __restrict__ z, u16* __restrict__ w, int K, int dqB,
                     const float* __restrict__ x, u16* __restrict__ xb) {
  const int bid = blockIdx.x;
  if (bid < dqB) {
    const int cpr = K >> 11;              // chunks per row (2048 elems each)
    const int row = bid / cpr;
    const int k = (bid % cpr) * 2048 + (int)threadIdx.x * 8;
    const int ng = K >> 7;
    const int g = k >> 7;
    const float sv = s[(size_t)row * ng + g];
    const float zv = (float)z[(size_t)row * ng + g];
    const int4* qp = (const int4*)(q + (size_t)row * K + k);
    const int4 a = qp[0], b = qp[1];
    u16x8 o;
    o[0] = f2bf(((float)a.x - zv) * sv);
    o[1] = f2bf(((float)a.y - zv) * sv);
    o[2] = f2bf(((float)a.z - zv) * sv);
    o[3] = f2bf(((float)a.w - zv) * sv);
    o[4] = f2bf(((float)b.x - zv) * sv);
    o[5] = f2bf(((float)b.y - zv) * sv);
    o[6] = f2bf(((float)b.z - zv) * sv);
    o[7] = f2bf(((float)b.w - zv) * sv);
    *reinterpret_cast<u16x8*>(w + (size_t)row * K + k) = o;
  } else {
    const size_t i = ((size_t)(bid - dqB) * 256 + threadIdx.x) << 3;
    const float4* p = (const float4*)(x + i);
    const float4 a = p[0], b = p[1];
    u16x8 o;
    o[0] = f2bf(a.x); o[1] = f2bf(a.y); o[2] = f2bf(a.z); o[3] = f2bf(a.w);
    o[4] = f2bf(b.x); o[5] = f2bf(b.y); o[6] = f2bf(b.z); o[7] = f2bf(b.w);
    *reinterpret_cast<u16x8*>(xb + i) = o;
  }
}

// ---------------- standalone dequant (serial fallback path only)
__global__ __launch_bounds__(256)
void dequant_kernel(const int* __restrict__ q, const float* __restrict__ s,
                    const int* __restrict__ z, u16* __restrict__ w, int K) {
  const int row = blockIdx.y;
  const int k = (blockIdx.x * 256 + threadIdx.x) << 3;
  const int ng = K >> 7;
  const int g = k >> 7;
  const float sv = s[(size_t)row * ng + g];
  const float zv = (float)z[(size_t)row * ng + g];
  const int4* qp = (const int4*)(q + (size_t)row * K + k);
  const int4 a = qp[0], b = qp[1];
  u16x8 o;
  o[0] = f2bf(((float)a.x - zv) * sv);
  o[1] = f2bf(((float)a.y - zv) * sv);
  o[2] = f2bf(((float)a.z - zv) * sv);
  o[3] = f2bf(((float)a.w - zv) * sv);
  o[4] = f2bf(((float)b.x - zv) * sv);
  o[5] = f2bf(((float)b.y - zv) * sv);
  o[6] = f2bf(((float)b.z - zv) * sv);
  o[7] = f2bf(((float)b.w - zv) * sv);
  *reinterpret_cast<u16x8*>(w + (size_t)row * K + k) = o;
}

// ---------------- 256x256 GEMM (R11 schedule) + optional fused dequant role
// FINAL (R19 measured best: 919.5us total, absmax 32, bank-conflicts 0).
// GEMM role: blocks [0, gemmNwg); R11 counted-lgkm 4-phase schedule.
// Dequant role: blocks [gemmNwg, ...) — 2 rows of q2 [.. x 14336] -> w2 each;
// dispatched after all GEMM blocks -> fills GEMM1's half-empty tail round.
// Closed-axes ledger (measured, do not retry): per-phase lgkm(0) full drains
// (R4-R8, the bottleneck counted waits fixed); NT stores = 2.2x write amp (R12);
// ph4 pre-issue = +15us/GEMM (R13); merged ph3/4 = neutral (R14); 32x32x16 =
// 4.4e7 bank conflicts (R15); lgkm(12) minimal wait = neutral (R16); BM=128 =
// 2x B-fetch (R9); m-fastest block order = regression (R7); BK=32 2-blocks/CU =
// acc[8][4]=128 VGPR > 128-cap -> scratch spill, 6.9x regression (R20: occupancy
// is register-walled; 256x256/8-wave is the unique geometry optimum).
template<bool RELU2>
__global__ __launch_bounds__(512, 2)
void gemm256(const u16* __restrict__ Ap, const u16* __restrict__ Bp,
             void* __restrict__ Cptr, int M, int N, int K, int gemmNwg,
             const int* __restrict__ q2, const float* __restrict__ s2,
             const int* __restrict__ z2, u16* __restrict__ w2) {
  __shared__ __align__(16) u16 As[2][256][64];
  __shared__ __align__(16) u16 Bs[2][256][64];

  if ((int)blockIdx.x >= gemmNwg) {
    // ---- dequant role: rows 2b, 2b+1 of q2 [.. x 14336] -> w2 ----
    const int b = (int)blockIdx.x - gemmNwg;
    const int I2 = 14336, ng = I2 >> 7;
#pragma unroll
    for (int itc = 0; itc < 7; ++itc) {
      const int inner = itc * 4096 + (int)threadIdx.x * 8;   // [0, 28672)
      const int r = (inner >= I2) ? 1 : 0;
      const int k = inner - r * I2;
      const int row = 2 * b + r;
      const int g = k >> 7;
      const float sv = s2[(size_t)row * ng + g];
      const float zv = (float)z2[(size_t)row * ng + g];
      const int4* qp = (const int4*)(q2 + (size_t)row * I2 + k);
      const int4 qa = qp[0], qb = qp[1];
      u16x8 o;
      o[0] = f2bf(((float)qa.x - zv) * sv);
      o[1] = f2bf(((float)qa.y - zv) * sv);
      o[2] = f2bf(((float)qa.z - zv) * sv);
      o[3] = f2bf(((float)qa.w - zv) * sv);
      o[4] = f2bf(((float)qb.x - zv) * sv);
      o[5] = f2bf(((float)qb.y - zv) * sv);
      o[6] = f2bf(((float)qb.z - zv) * sv);
      o[7] = f2bf(((float)qb.w - zv) * sv);
      *reinterpret_cast<u16x8*>(w2 + (size_t)row * I2 + k) = o;
    }
    return;
  }

  const int tid = threadIdx.x;
  const int lane = tid & 63;
  const int wid = tid >> 6;
  const int wr = wid >> 2, wc = wid & 3;

  const int nbx = N >> 8;
  const int nwg = gemmNwg;
  int bid = blockIdx.x;
  bid = (bid & 7) * (nwg >> 3) + (bid >> 3);   // XCD swizzle (gemmNwg % 8 == 0)
  const int m0 = (bid / nbx) << 8;             // n-fastest (R6 order)
  const int n0 = (bid % nbx) << 8;

  const int srow = tid >> 3;        // staging row within 64-row sweep
  const int scol = tid & 7;         // staging 16B segment
  const int lr = lane & 15;
  const int lk = (lane >> 4) << 3;
  const int xorc = (lr & 7) << 3;   // read-side swizzle (row&7 == lr&7)

  // ds_read bases: row base per (array, buf); k byte-offset koff0 / koff0^64
  const char* baA0 = (const char*)&As[0][0][0] + (wr * 128 + lr) * 128;
  const char* baA1 = baA0 + 32768;
  const char* baB0 = (const char*)&Bs[0][0][0] + (wc * 64 + lr) * 128;
  const char* baB1 = baB0 + 32768;
  const int koff0 = (lk ^ xorc) * 2;

  f32x4 acc[8][4] = {};
  bf16x8 a1[4], a2[4], a3[4], a4[4], b1[4], b2[4];

  const int nk = K >> 6;

#define STG_A(bufi, h, kt) do { _Pragma("unroll") \
  for (int l_ = 0; l_ < 2; ++l_) { \
    const int r_ = (h) * 128 + l_ * 64 + srow; \
    gload_lds16(Ap + (size_t)(m0 + r_) * K + (size_t)((kt) << 6) + ((scol ^ (srow & 7)) << 3), \
                &As[bufi][r_][scol << 3]); } } while (0)
#define STG_B(bufi, h, kt) do { _Pragma("unroll") \
  for (int l_ = 0; l_ < 2; ++l_) { \
    const int r_ = (h) * 128 + l_ * 64 + srow; \
    gload_lds16(Bp + (size_t)(n0 + r_) * K + (size_t)((kt) << 6) + ((scol ^ (srow & 7)) << 3), \
                &Bs[bufi][r_][scol << 3]); } } while (0)
#define RD_A(base, ks, half, dst) do { _Pragma("unroll") \
  for (int i_ = 0; i_ < 4; ++i_) \
    dst[i_] = *reinterpret_cast<const bf16x8*>( \
      (base) + ((half) * 4 + i_) * 2048 + (koff0 ^ ((ks) * 64))); } while (0)
#define RD_B(base, ks, dst) do { _Pragma("unroll") \
  for (int j_ = 0; j_ < 4; ++j_) \
    dst[j_] = *reinterpret_cast<const bf16x8*>( \
      (base) + j_ * 2048 + (koff0 ^ ((ks) * 64))); } while (0)
#define MFMA16(ASET, BSET, I0) do { _Pragma("unroll") \
  for (int i_ = 0; i_ < 4; ++i_) { _Pragma("unroll") \
    for (int j_ = 0; j_ < 4; ++j_) \
      acc[(I0) + i_][j_] = __builtin_amdgcn_mfma_f32_16x16x32_bf16( \
        ASET[i_], BSET[j_], acc[(I0) + i_][j_], 0, 0, 0); } } while (0)
#define BARO() do { asm volatile("" ::: "memory"); __builtin_amdgcn_s_barrier(); \
  asm volatile("" ::: "memory"); } while (0)
#define LGKM(n) do { asm volatile("s_waitcnt lgkmcnt(" #n ")" ::: "memory"); \
  __builtin_amdgcn_sched_barrier(0); } while (0)
#define SB0 __builtin_amdgcn_sched_barrier(0)
#define GATE4 asm volatile("s_waitcnt vmcnt(4)" ::: "memory")
#define PRIO(Q) do { __builtin_amdgcn_s_setprio(1); Q; __builtin_amdgcn_s_setprio(0); } while (0)
#define TILE4(bA, bB, SA1, SA2, SB3, SB4) do { \
  BARO(); \
  RD_B(bB, 0, b1); RD_A(bA, 0, 0, a1); \
  LGKM(0); \
  SA1; \
  PRIO(MFMA16(a1, b1, 0)); \
  SB0; RD_B(bB, 1, b2); SB0; RD_A(bA, 0, 1, a2); SB0; RD_A(bA, 1, 1, a4); SB0; RD_A(bA, 1, 0, a3); \
  BARO(); \
  LGKM(8); \
  SA2; \
  PRIO(MFMA16(a2, b1, 4)); \
  BARO(); \
  LGKM(4); \
  SB3; \
  PRIO(MFMA16(a4, b2, 4)); \
  BARO(); \
  LGKM(0); \
  SB4; \
  PRIO(MFMA16(a3, b2, 0)); \
  GATE4; \
} while (0)

  // prologue: A(0),B(0)->buf0, B(1)->buf1 (12 loads); vmcnt(4) leaves B(1) in flight
  STG_A(0, 0, 0); STG_A(0, 1, 0);
  STG_B(0, 0, 0); STG_B(0, 1, 0);
  STG_B(1, 0, 1); STG_B(1, 1, 1);
  asm volatile("s_waitcnt vmcnt(4)" ::: "memory");

  const int nit = nk >> 1;
  for (int it = 0; it < nit; ++it) {
    const int t1 = 2 * it + 1;
    int t2 = 2 * it + 2; if (t2 >= nk) t2 -= nk;   // wrap: tail stages are dummies
    int t3 = 2 * it + 3; if (t3 >= nk) t3 -= nk;
    TILE4(baA0, baB0, STG_A(1, 0, t1), STG_A(1, 1, t1), STG_B(0, 0, t2), STG_B(0, 1, t2));
    TILE4(baA1, baB1, STG_A(0, 0, t2), STG_A(0, 1, t2), STG_B(1, 0, t3), STG_B(1, 1, t3));
  }
  asm volatile("s_waitcnt vmcnt(0) lgkmcnt(0)" ::: "memory");  // drain dummies before epilogue

  // epilogue: C/D layout col = lane&15, row = (lane>>4)*4 + reg  [m89-verified]
  const int crow = (lane >> 4) << 2;
  const int ccol = lane & 15;
#pragma unroll
  for (int i = 0; i < 8; ++i) {
#pragma unroll
    for (int j = 0; j < 4; ++j) {
#pragma unroll
      for (int q = 0; q < 4; ++q) {
        const int m = m0 + wr * 128 + i * 16 + crow + q;
        const int n = n0 + wc * 64 + j * 16 + ccol;
        const float v = acc[i][j][q];
        if constexpr (RELU2) {
          const float r = fmaxf(v, 0.f);
          ((u16*)Cptr)[(size_t)m * N + n] = f2bf(r * r);
        } else {
          ((float*)Cptr)[(size_t)m * N + n] = v;
        }
      }
    }
  }
#undef STG_A
#undef STG_B
#undef RD_A
#undef RD_B
#undef MFMA16
#undef BARO
#undef LGKM
#undef SB0
#undef GATE4
#undef PRIO
#undef TILE4
}

extern "C" void kernel_launch(void* const* d_in, const int* in_sizes, int n_in,
                              void* d_out, int out_size, void* d_ws, size_t ws_size,
                              hipStream_t stream) {
  const float* x    = (const float*)d_in[0];
  const int*   q_up = (const int*)d_in[1];
  const float* s_up = (const float*)d_in[2];
  const int*   z_up = (const int*)d_in[3];
  const int*   q_dn = (const int*)d_in[4];
  const float* s_dn = (const float*)d_in[5];
  const int*   z_dn = (const int*)d_in[6];
  float* y = (float*)d_out;

  const int H = 4096, I = 14336;
  const int M = in_sizes[0] / H;  // 4096 tokens

  const size_t wbytes = (size_t)I * H * 2;   // 117.4 MB bf16 weight buffer
  const size_t abytes = (size_t)M * I * 2;   // 117.4 MB bf16 activations
  const size_t xbytes = (size_t)M * H * 2;   // 33.5 MB bf16 x
  u16* wbuf  = (u16*)d_ws;
  u16* abuf  = (u16*)((char*)d_ws + wbytes);
  u16* xbf   = (u16*)((char*)d_ws + wbytes + abytes);
  u16* wbuf2 = (u16*)((char*)d_ws + wbytes + abytes + xbytes);  // W_down (fused path)
  if (ws_size < wbytes + abytes + xbytes) return;  // insufficient scratch: fail cleanly
  const bool fused = ws_size >= 2 * wbytes + abytes + xbytes;

  const int dqB = I * (H >> 11);                      // 28672 dequant blocks
  const int cvB = (int)(((size_t)M * H) >> 11);       // 8192 cvt blocks
  // 1. fused prologue: dequant W_up + cvt x (one launch)
  prologue_kernel<<<dim3(dqB + cvB), 256, 0, stream>>>(q_up, s_up, z_up, wbuf, H, dqB, x, xbf);

  const int g1 = (M / 256) * (I / 256);   // 896, %8==0
  const int g2 = (M / 256) * (H / 256);   // 256, %8==0
  if (fused) {
    // 2. a = relu(x @ W_up^T)^2  WITH dequant2(W_down -> wbuf2) in trailing blocks
    gemm256<true><<<dim3(g1 + H / 2), 512, 0, stream>>>(
        xbf, wbuf, abuf, M, I, H, g1, q_dn, s_dn, z_dn, wbuf2);
    // 3. y = a @ W_down^T, fp32
    gemm256<false><<<dim3(g2), 512, 0, stream>>>(
        abuf, wbuf2, y, M, H, I, g2, nullptr, nullptr, nullptr, nullptr);
  } else {
    // serial fallback (R11 path, 952us)
    gemm256<true><<<dim3(g1), 512, 0, stream>>>(
        xbf, wbuf, abuf, M, I, H, g1, nullptr, nullptr, nullptr, nullptr);
    dequant_kernel<<<dim3(I / 8 / 256, H), 256, 0, stream>>>(q_dn, s_dn, z_dn, wbuf, I);
    gemm256<false><<<dim3(g2), 512, 0, stream>>>(
        abuf, wbuf, y, M, H, I, g2, nullptr, nullptr, nullptr, nullptr);
  }
}